// Round 11
// baseline (160.354 us; speedup 1.0000x reference)
//
#include <hip/hip_runtime.h>
#include <hip/hip_bf16.h>
#include <cstdint>

#define DEVI __device__ __forceinline__

typedef __attribute__((ext_vector_type(8))) short bf16x8;
typedef __attribute__((ext_vector_type(4))) short bf16x4;
typedef __attribute__((ext_vector_type(4))) float f32x4;

DEVI short f2bf(float f) {
  unsigned u = __float_as_uint(f);
  u += 0x7fff + ((u >> 16) & 1);   // round-to-nearest-even
  return (short)(u >> 16);
}
DEVI float bf2f(short s) { return __uint_as_float(((unsigned)(unsigned short)s) << 16); }

DEVI void gl_lds16(const short* g, short* l) {
  __builtin_amdgcn_global_load_lds((const __attribute__((address_space(1))) unsigned*)g,
                                   (__attribute__((address_space(3))) unsigned*)l, 16, 0, 0);
}

// ===========================================================================
// Ladder status (R20-R26, measured), K=1024-class GEMMs:
//   occ-2 dbuf(drain0) 372-614 TF | occ-4/6 SB 662-715 TF (plateau)
//   R25 L2-banding: null (concurrency width >> band window)
//   R26 counted-vmcnt dbuf occ-3: 54->62us REGRESSION (occupancy loss >
//   pipeline gain; 8-phase needs K-depth that K=16-steps lacks)
// => ~660-700 TF is this structure family's floor for the shape. sz2
// REVERTED to R25 SB occ-6. R27: PV -> 128x64 core (stage/FLOP x0.75,
// LDS-read/FLOP x0.67 vs 64^2).
// ===========================================================================

// ---------------------------------------------------------------------------
// gemm_ww: BOTH split-K weight precomputes in one dispatch (512 wgs).
//   job 0: partM[z] = WkBf @ WqBf^T  (k-quarter z)
//   job 1: partW[z] = WoT  @ WvBf^T
// ---------------------------------------------------------------------------
__global__ __launch_bounds__(256, 4)
void gemm_ww(const short* __restrict__ WkBf, const short* __restrict__ WqBf,
             const short* __restrict__ WoT, const short* __restrict__ WvBf,
             float* __restrict__ partM, float* __restrict__ partW)
{
  const int orig = blockIdx.x;                  // 512 wgs
  const int xcd = orig & 7, idx8 = orig >> 3;
  const int wg = xcd * 64 + idx8;               // q8=64
  const int job = wg >> 8, rem = wg & 255;
  const int z = rem >> 6, t = rem & 63;
  const int bi = t >> 3, bj = t & 7;

  const short* A = job ? WoT  : WkBf;
  const short* B = job ? WvBf : WqBf;
  float* Cf = (job ? partW : partM) + (long long)z * 1048576;

  __shared__ __align__(16) short lA[128 * 64];  // 16 KB
  __shared__ __align__(16) short lB[128 * 64];  // 16 KB

  const int tid = threadIdx.x, wave = tid >> 6, lane = tid & 63;
  const int wr = wave >> 1, wc = wave & 1;
  const int brow = bi * 128, bcol = bj * 128;
  const int fr = lane & 15, h = lane >> 4;

  const int ck0 = ((h ^ (fr & 7))) * 8;
  const int swc = ((tid & 7) ^ ((tid >> 3) & 7)) * 8;
  const short* pA = A + (long long)(brow + (tid >> 3)) * 1024 + swc;
  const short* pB = B + (long long)(bcol + (tid >> 3)) * 1024 + swc;

  f32x4 acc[4][4] = {};
  const long long ko0 = (long long)z * 256;

  for (int t2 = 0; t2 < 4; ++t2) {
    const long long ko = ko0 + t2 * 64;
#pragma unroll
    for (int j = 0; j < 4; ++j)
      gl_lds16(pA + (long long)(j * 32) * 1024 + ko, &lA[j * 2048 + tid * 8]);
#pragma unroll
    for (int j = 0; j < 4; ++j)
      gl_lds16(pB + (long long)(j * 32) * 1024 + ko, &lB[j * 2048 + tid * 8]);
    __syncthreads();

    bf16x8 af[4], bg[4];
#pragma unroll
    for (int m = 0; m < 4; ++m)
      af[m] = *(const bf16x8*)&lA[(wr * 64 + m * 16 + fr) * 64 + ck0];
#pragma unroll
    for (int n = 0; n < 4; ++n)
      bg[n] = *(const bf16x8*)&lB[(wc * 64 + n * 16 + fr) * 64 + ck0];
#pragma unroll
    for (int m = 0; m < 4; ++m)
#pragma unroll
      for (int n = 0; n < 4; ++n)
        acc[m][n] = __builtin_amdgcn_mfma_f32_16x16x32_bf16(af[m], bg[n], acc[m][n], 0, 0, 0);
#pragma unroll
    for (int m = 0; m < 4; ++m)
      af[m] = *(const bf16x8*)&lA[((wr * 64 + m * 16 + fr) * 64 + ck0) ^ 32];
#pragma unroll
    for (int n = 0; n < 4; ++n)
      bg[n] = *(const bf16x8*)&lB[((wc * 64 + n * 16 + fr) * 64 + ck0) ^ 32];
#pragma unroll
    for (int m = 0; m < 4; ++m)
#pragma unroll
      for (int n = 0; n < 4; ++n)
        acc[m][n] = __builtin_amdgcn_mfma_f32_16x16x32_bf16(af[m], bg[n], acc[m][n], 0, 0, 0);
    __syncthreads();
  }

  const int lrow = h * 4;
#pragma unroll
  for (int m = 0; m < 4; ++m) {
    const int row = brow + wr * 64 + m * 16 + lrow;
#pragma unroll
    for (int j = 0; j < 4; ++j)
#pragma unroll
      for (int n = 0; n < 4; ++n)
        Cf[(long long)(row + j) * 1024 + bcol + wc * 64 + n * 16 + fr] = acc[m][n][j];
  }
}

// combine both split-K results: wg<1024 -> MTb, else WvoT (1M elems each)
__global__ __launch_bounds__(256)
void combine_ww(const float* __restrict__ partM, const float* __restrict__ partW,
                short* __restrict__ MTb, short* __restrict__ WvoT)
{
  const int wg = blockIdx.x;
  const float* p = (wg < 1024) ? partM : partW;
  short* out = (wg < 1024) ? MTb : WvoT;
  const long long i = (long long)(wg & 1023) * 256 + threadIdx.x;  // float4 idx
  const float4 a = ((const float4*)p)[i];
  const float4 b = ((const float4*)(p + 1048576))[i];
  const float4 c = ((const float4*)(p + 2097152))[i];
  const float4 d = ((const float4*)(p + 3145728))[i];
  bf16x4 o;
  o[0] = f2bf(a.x + b.x + c.x + d.x);
  o[1] = f2bf(a.y + b.y + c.y + d.y);
  o[2] = f2bf(a.z + b.z + c.z + d.z);
  o[3] = f2bf(a.w + b.w + c.w + d.w);
  ((bf16x4*)out)[i] = o;
}

// ---------------------------------------------------------------------------
// gemm_g2: G = (ybf @ MTb^T + wvec)/32. 128x64 tiles, occ-6, 1024 wgs.
// ---------------------------------------------------------------------------
__global__ __launch_bounds__(256, 6)
void gemm_g2(const short* __restrict__ ybf, const short* __restrict__ MTb,
             short* __restrict__ G, const float* __restrict__ wvec)
{
  const int orig = blockIdx.x;                  // 1024 wgs
  const int xcd = orig & 7, idx8 = orig >> 3;
  const int wg = xcd * 128 + idx8;              // q8=128
  const int bi = wg >> 4, bj = wg & 15;         // 64 row-tiles x 16 col-tiles

  __shared__ __align__(16) short lA[128 * 64];  // 16 KB
  __shared__ __align__(16) short lB[64 * 64];   // 8 KB

  const int tid = threadIdx.x, wave = tid >> 6, lane = tid & 63;
  const int wr = wave >> 1, wc = wave & 1;
  const int brow = bi * 128, bcol = bj * 64;
  const int fr = lane & 15, h = lane >> 4;

  const int ck0 = ((h ^ (fr & 7))) * 8;
  const int swc = ((tid & 7) ^ ((tid >> 3) & 7)) * 8;
  const short* pA = ybf + (long long)(brow + (tid >> 3)) * 1024 + swc;
  const short* pB = MTb + (long long)(bcol + (tid >> 3)) * 1024 + swc;

  f32x4 acc[4][2] = {};

  for (int t = 0; t < 16; ++t) {
    const long long ko = (long long)t * 64;
#pragma unroll
    for (int j = 0; j < 4; ++j)
      gl_lds16(pA + (long long)(j * 32) * 1024 + ko, &lA[j * 2048 + tid * 8]);
#pragma unroll
    for (int j = 0; j < 2; ++j)
      gl_lds16(pB + (long long)(j * 32) * 1024 + ko, &lB[j * 2048 + tid * 8]);
    __syncthreads();

    bf16x8 af[4], bg[2];
#pragma unroll
    for (int m = 0; m < 4; ++m)
      af[m] = *(const bf16x8*)&lA[(wr * 64 + m * 16 + fr) * 64 + ck0];
#pragma unroll
    for (int n = 0; n < 2; ++n)
      bg[n] = *(const bf16x8*)&lB[(wc * 32 + n * 16 + fr) * 64 + ck0];
#pragma unroll
    for (int m = 0; m < 4; ++m)
#pragma unroll
      for (int n = 0; n < 2; ++n)
        acc[m][n] = __builtin_amdgcn_mfma_f32_16x16x32_bf16(af[m], bg[n], acc[m][n], 0, 0, 0);
#pragma unroll
    for (int m = 0; m < 4; ++m)
      af[m] = *(const bf16x8*)&lA[((wr * 64 + m * 16 + fr) * 64 + ck0) ^ 32];
#pragma unroll
    for (int n = 0; n < 2; ++n)
      bg[n] = *(const bf16x8*)&lB[((wc * 32 + n * 16 + fr) * 64 + ck0) ^ 32];
#pragma unroll
    for (int m = 0; m < 4; ++m)
#pragma unroll
      for (int n = 0; n < 2; ++n)
        acc[m][n] = __builtin_amdgcn_mfma_f32_16x16x32_bf16(af[m], bg[n], acc[m][n], 0, 0, 0);
    __syncthreads();
  }

  const int lrow = h * 4;
  int colg[2]; float bvv[2];
#pragma unroll
  for (int n = 0; n < 2; ++n) {
    colg[n] = bcol + wc * 32 + n * 16 + fr;
    bvv[n] = wvec[colg[n]];
  }
#pragma unroll
  for (int m = 0; m < 4; ++m) {
    const int row = brow + wr * 64 + m * 16 + lrow;
#pragma unroll
    for (int j = 0; j < 4; ++j)
#pragma unroll
      for (int n = 0; n < 2; ++n)
        G[(long long)(row + j) * 1024 + colg[n]] =
            f2bf((acc[m][n][j] + bvv[n]) * (1.f / 32.f));
  }
}

// ---------------------------------------------------------------------------
// gemm_sz2: merged scores+zT, 128x64 tiles, occ-6, 2112 wgs (R25 version —
// proven 54.2us; R26 counted-vmcnt dbuf reverted: 62us regression).
// ---------------------------------------------------------------------------
__global__ __launch_bounds__(256, 6)
void gemm_sz2(const short* __restrict__ G, const short* __restrict__ ybf,
              const short* __restrict__ WvoT, short* __restrict__ scores,
              short* __restrict__ zT)
{
  const int orig = blockIdx.x;                  // 2112 wgs
  const int xcd = orig & 7, idx8 = orig >> 3;
  const int wg = xcd * 264 + idx8;              // q8=264

  const short *A, *B; short* C; int ldc, bi, bj;
  if (wg < 1088) {
    const int z = wg / 272, t = wg - z * 272;
    // banded decode: k = band (4 bi-rows), u = index within band
    const int k = (t >= 20) + (t >= 72) + (t >= 156);
    const int u = t - (16 * k * k + 4 * k);
    int r, col;
    if (u < 32 * k) {                 // full 8-col blocks
      const int cb = u >> 5, w = u & 31;
      r = w >> 3; col = cb * 8 + (w & 7);
    } else {                          // ragged diagonal block (2/4/6/8 cols)
      const int u2 = u - 32 * k;
      r = (u2 >= 2) + (u2 >= 6) + (u2 >= 12);
      const int cum = (r == 0) ? 0 : (r == 1) ? 2 : (r == 2) ? 6 : 12;
      col = 8 * k + (u2 - cum);
    }
    bi = 4 * k + r; bj = col;
    A = G + (long long)z * 2048 * 1024;
    B = ybf + (long long)z * 2048 * 1024;
    C = scores + (long long)z * 2048 * 2048;
    ldc = 2048;
  } else {
    const int lwg = wg - 1088;
    bi = lwg >> 7; bj = lwg & 127;
    A = WvoT; B = ybf; C = zT; ldc = 8192;
  }

  __shared__ __align__(16) short lA[128 * 64];  // 16 KB
  __shared__ __align__(16) short lB[64 * 64];   // 8 KB

  const int tid = threadIdx.x, wave = tid >> 6, lane = tid & 63;
  const int wr = wave >> 1, wc = wave & 1;
  const int brow = bi * 128, bcol = bj * 64;
  const int fr = lane & 15, h = lane >> 4;

  const int ck0 = ((h ^ (fr & 7))) * 8;
  const int swc = ((tid & 7) ^ ((tid >> 3) & 7)) * 8;
  const short* pA = A + (long long)(brow + (tid >> 3)) * 1024 + swc;
  const short* pB = B + (long long)(bcol + (tid >> 3)) * 1024 + swc;

  f32x4 acc[4][2] = {};

  for (int t = 0; t < 16; ++t) {
    const long long ko = (long long)t * 64;
#pragma unroll
    for (int j = 0; j < 4; ++j)
      gl_lds16(pA + (long long)(j * 32) * 1024 + ko, &lA[j * 2048 + tid * 8]);
#pragma unroll
    for (int j = 0; j < 2; ++j)
      gl_lds16(pB + (long long)(j * 32) * 1024 + ko, &lB[j * 2048 + tid * 8]);
    __syncthreads();

    bf16x8 af[4], bg[2];
#pragma unroll
    for (int m = 0; m < 4; ++m)
      af[m] = *(const bf16x8*)&lA[(wr * 64 + m * 16 + fr) * 64 + ck0];
#pragma unroll
    for (int n = 0; n < 2; ++n)
      bg[n] = *(const bf16x8*)&lB[(wc * 32 + n * 16 + fr) * 64 + ck0];
#pragma unroll
    for (int m = 0; m < 4; ++m)
#pragma unroll
      for (int n = 0; n < 2; ++n)
        acc[m][n] = __builtin_amdgcn_mfma_f32_16x16x32_bf16(af[m], bg[n], acc[m][n], 0, 0, 0);
#pragma unroll
    for (int m = 0; m < 4; ++m)
      af[m] = *(const bf16x8*)&lA[((wr * 64 + m * 16 + fr) * 64 + ck0) ^ 32];
#pragma unroll
    for (int n = 0; n < 2; ++n)
      bg[n] = *(const bf16x8*)&lB[((wc * 32 + n * 16 + fr) * 64 + ck0) ^ 32];
#pragma unroll
    for (int m = 0; m < 4; ++m)
#pragma unroll
      for (int n = 0; n < 2; ++n)
        acc[m][n] = __builtin_amdgcn_mfma_f32_16x16x32_bf16(af[m], bg[n], acc[m][n], 0, 0, 0);
    __syncthreads();
  }

  const int lrow = h * 4;
  int colg[2];
#pragma unroll
  for (int n = 0; n < 2; ++n) colg[n] = bcol + wc * 32 + n * 16 + fr;
#pragma unroll
  for (int m = 0; m < 4; ++m) {
    const int row = brow + wr * 64 + m * 16 + lrow;
#pragma unroll
    for (int j = 0; j < 4; ++j)
#pragma unroll
      for (int n = 0; n < 2; ++n)
        C[(long long)(row + j) * ldc + colg[n]] = f2bf(acc[m][n][j]);
  }
}

// ===========================================================================
// R27 PV: 128x64 tiles (sz2's proven core), 1024 wgs = 4/CU (gemm_zg proved
// 4/CU SB ~715 TF). Parity-mixed decode: bi = ((idx8>>4)<<1)|((xcd&1)^(idx8&1))
// -> per-XCD Σnt exactly equal (2176 steps). Causal kend=(bi+1)*128.
// out = P @ z + (bo + bvWo), final fp32.
// ===========================================================================
__global__ __launch_bounds__(256, 6)
void gemm_pv(const short* __restrict__ scores, const short* __restrict__ zT,
             float* __restrict__ out, const float* __restrict__ bo,
             const float* __restrict__ bvWo)
{
  const int orig = blockIdx.x;                 // 1024 wgs
  const int xcd = orig & 7, idx8 = orig >> 3;  // idx8 in [0,128)
  const int z = xcd >> 1;                      // batch 0..3
  const int bi = ((idx8 >> 4) << 1) | ((xcd & 1) ^ (idx8 & 1));  // 0..15
  const int bj = idx8 & 15;                    // 0..15

  const short* A = scores + (long long)z * 2048 * 2048;
  const int nt = 2 * (bi + 1);                 // kend = (bi+1)*128, causal

  __shared__ __align__(16) short lA[128 * 64]; // 16 KB
  __shared__ __align__(16) short lB[64 * 64];  // 8 KB

  const int tid = threadIdx.x, wave = tid >> 6, lane = tid & 63;
  const int wr = wave >> 1, wc = wave & 1;
  const int brow = bi * 128, bcol = bj * 64;
  const int fr = lane & 15, h = lane >> 4;

  const int ck0 = ((h ^ (fr & 7))) * 8;
  const int swc = ((tid & 7) ^ ((tid >> 3) & 7)) * 8;
  const short* pA = A + (long long)(brow + (tid >> 3)) * 2048 + swc;
  const short* pB = zT + (long long)(bcol + (tid >> 3)) * 8192 + z * 2048 + swc;

  f32x4 acc[4][2] = {};

  for (int t = 0; t < nt; ++t) {
    const long long ko = (long long)t * 64;
#pragma unroll
    for (int j = 0; j < 4; ++j)
      gl_lds16(pA + (long long)(j * 32) * 2048 + ko, &lA[j * 2048 + tid * 8]);
#pragma unroll
    for (int j = 0; j < 2; ++j)
      gl_lds16(pB + (long long)(j * 32) * 8192 + ko, &lB[j * 2048 + tid * 8]);
    __syncthreads();

    bf16x8 af[4], bg[2];
#pragma unroll
    for (int m = 0; m < 4; ++m)
      af[m] = *(const bf16x8*)&lA[(wr * 64 + m * 16 + fr) * 64 + ck0];
#pragma unroll
    for (int n = 0; n < 2; ++n)
      bg[n] = *(const bf16x8*)&lB[(wc * 32 + n * 16 + fr) * 64 + ck0];
#pragma unroll
    for (int m = 0; m < 4; ++m)
#pragma unroll
      for (int n = 0; n < 2; ++n)
        acc[m][n] = __builtin_amdgcn_mfma_f32_16x16x32_bf16(af[m], bg[n], acc[m][n], 0, 0, 0);
#pragma unroll
    for (int m = 0; m < 4; ++m)
      af[m] = *(const bf16x8*)&lA[((wr * 64 + m * 16 + fr) * 64 + ck0) ^ 32];
#pragma unroll
    for (int n = 0; n < 2; ++n)
      bg[n] = *(const bf16x8*)&lB[((wc * 32 + n * 16 + fr) * 64 + ck0) ^ 32];
#pragma unroll
    for (int m = 0; m < 4; ++m)
#pragma unroll
      for (int n = 0; n < 2; ++n)
        acc[m][n] = __builtin_amdgcn_mfma_f32_16x16x32_bf16(af[m], bg[n], acc[m][n], 0, 0, 0);
    __syncthreads();
  }

  const int lrow = h * 4;
  int colg[2]; float bvv[2];
#pragma unroll
  for (int n = 0; n < 2; ++n) {
    colg[n] = bcol + wc * 32 + n * 16 + fr;
    bvv[n] = bo[colg[n]] + bvWo[colg[n]];
  }
#pragma unroll
  for (int m = 0; m < 4; ++m) {
    const int row = brow + wr * 64 + m * 16 + lrow;
#pragma unroll
    for (int j = 0; j < 4; ++j)
#pragma unroll
      for (int n = 0; n < 2; ++n)
        out[(long long)(z * 2048 + row + j) * 1024 + colg[n]] = acc[m][n][j] + bvv[n];
  }
}

// ---------------------------------------------------------------------------
// Causal-trimmed softmax. wlim now 128-aligned: PV's 128-row tiles read cols
// < (bi+1)*128, so the masked band up to the 128 boundary must hold zeros.
__global__ __launch_bounds__(256)
void softmax_causal_bf16_k(short* __restrict__ sc)
{
  const int T = 2048;
  const long long row = blockIdx.x;
  const int t = (int)(row & (T - 1));
  short* ps = sc + row * (long long)T;
  const int tid = threadIdx.x, wave = tid >> 6, lane = tid & 63;
  const int c0 = tid * 8;
  const int wlim = ((t >> 7) + 1) << 7;   // exclusive write limit, 128-aligned

  bf16x8 v = {};
  if (c0 <= t) v = *(const bf16x8*)&ps[c0];
  float x[8];
#pragma unroll
  for (int j = 0; j < 8; ++j) x[j] = bf2f(v[j]);

  float mx = -3.0e38f;
#pragma unroll
  for (int j = 0; j < 8; ++j) if (c0 + j <= t) mx = fmaxf(mx, x[j]);
#pragma unroll
  for (int o = 32; o; o >>= 1) mx = fmaxf(mx, __shfl_xor(mx, o, 64));
  __shared__ float red[8];
  if (lane == 0) red[wave] = mx;
  __syncthreads();
  const float M = fmaxf(fmaxf(red[0], red[1]), fmaxf(red[2], red[3]));

  float e[8], s = 0.f;
#pragma unroll
  for (int j = 0; j < 8; ++j) { e[j] = (c0 + j <= t) ? __expf(x[j] - M) : 0.f; s += e[j]; }
#pragma unroll
  for (int o = 32; o; o >>= 1) s += __shfl_xor(s, o, 64);
  if (lane == 0) red[4 + wave] = s;
  __syncthreads();
  const float inv = 1.f / (red[4] + red[5] + red[6] + red[7]);

  if (c0 < wlim) {
    bf16x8 ov;
#pragma unroll
    for (int j = 0; j < 8; ++j) ov[j] = f2bf(e[j] * inv);
    *(bf16x8*)&ps[c0] = ov;
  }
}

// ---------------------------------------------------------------------------
// cvt_all: ALL independent prep work in one dispatch (9280 wgs):
//   wg <  4096: y fp32 -> ybf
//   wg <  8192: weight converts (Wq/Wk/Wv plain, Wo transpose)
//   wg <  9216: wkbq GEMV row (wvec = Wk @ bq)
//   wg <  9280: bias_fold (bvWo += bv block @ Wo, atomics; pre-zeroed)
// ---------------------------------------------------------------------------
__global__ __launch_bounds__(256)
void cvt_all(const float* __restrict__ y, const float* __restrict__ Wq,
             const float* __restrict__ Wk, const float* __restrict__ Wo,
             const float* __restrict__ Wv, const float* __restrict__ bq,
             const float* __restrict__ bv,
             short* __restrict__ ybf, short* __restrict__ WqBf,
             short* __restrict__ WkBf, short* __restrict__ WoT,
             short* __restrict__ WvBf, float* __restrict__ wvec,
             float* __restrict__ bvWo)
{
  const int wg = blockIdx.x, tid = threadIdx.x;
  __shared__ float tile[32][33];
  __shared__ float red[4];

  if (wg < 4096) {                    // ---- y convert
    const long long i = (long long)wg * 256 + tid;
    const float4 v0 = ((const float4*)y)[i * 2];
    const float4 v1 = ((const float4*)y)[i * 2 + 1];
    bf16x8 o;
    o[0] = f2bf(v0.x); o[1] = f2bf(v0.y); o[2] = f2bf(v0.z); o[3] = f2bf(v0.w);
    o[4] = f2bf(v1.x); o[5] = f2bf(v1.y); o[6] = f2bf(v1.z); o[7] = f2bf(v1.w);
    ((bf16x8*)ybf)[i] = o;
  } else if (wg < 8192) {             // ---- weight converts
    const int lwg = wg - 4096;
    const int bx = lwg & 31, by = (lwg >> 5) & 31, bz = lwg >> 10;
    const int tx = tid & 31, ty = tid >> 5;
    const int r0 = by * 32, c0 = bx * 32;
    if (bz != 2) {
      const float* in = (bz == 0) ? Wq : (bz == 1 ? Wk : Wv);
      short* out      = (bz == 0) ? WqBf : (bz == 1 ? WkBf : WvBf);
#pragma unroll
      for (int i = 0; i < 4; ++i)
        out[(long long)(r0 + ty + 8 * i) * 1024 + c0 + tx] =
            f2bf(in[(long long)(r0 + ty + 8 * i) * 1024 + c0 + tx]);
    } else {
#pragma unroll
      for (int i = 0; i < 4; ++i)
        tile[ty + 8 * i][tx] = Wo[(long long)(r0 + ty + 8 * i) * 1024 + c0 + tx];
      __syncthreads();
#pragma unroll
      for (int i = 0; i < 4; ++i)
        WoT[(long long)(c0 + ty + 8 * i) * 1024 + r0 + tx] = f2bf(tile[tx][ty + 8 * i]);
    }
  } else if (wg < 9216) {             // ---- wkbq GEMV
    const int row = wg - 8192;
    const float4 a = ((const float4*)(Wk + (long long)row * 1024))[tid];
    const float4 b = ((const float4*)bq)[tid];
    float s = a.x * b.x + a.y * b.y + a.z * b.z + a.w * b.w;
#pragma unroll
    for (int o = 32; o; o >>= 1) s += __shfl_xor(s, o, 64);
    if ((tid & 63) == 0) red[tid >> 6] = s;
    __syncthreads();
    if (tid == 0) wvec[row] = red[0] + red[1] + red[2] + red[3];
  } else {                            // ---- bias fold (bvWo pre-zeroed)
    const int r0 = (wg - 9216) * 16;
    const int c4 = tid;
    float4 acc = make_float4(0.f, 0.f, 0.f, 0.f);
    for (int r = 0; r < 16; ++r) {
      const float s = bv[r0 + r];
      const float4 w = ((const float4*)(Wo + (long long)(r0 + r) * 1024))[c4];
      acc.x += s * w.x; acc.y += s * w.y; acc.z += s * w.z; acc.w += s * w.w;
    }
    atomicAdd(&bvWo[c4 * 4 + 0], acc.x);
    atomicAdd(&bvWo[c4 * 4 + 1], acc.y);
    atomicAdd(&bvWo[c4 * 4 + 2], acc.z);
    atomicAdd(&bvWo[c4 * 4 + 3], acc.w);
  }
}

// ---------------------------------------------------------------------------
extern "C" void kernel_launch(void* const* d_in, const int* in_sizes, int n_in,
                              void* d_out, int out_size, void* d_ws, size_t ws_size,
                              hipStream_t stream)
{
  (void)in_sizes; (void)n_in; (void)out_size; (void)ws_size;
  const float* y  = (const float*)d_in[0];
  const float* Wq = (const float*)d_in[1];
  const float* bq = (const float*)d_in[2];
  const float* Wk = (const float*)d_in[3];
  const float* bk = (const float*)d_in[4];
  const float* Wv = (const float*)d_in[5];
  const float* bv = (const float*)d_in[6];
  const float* Wo = (const float*)d_in[7];
  const float* bo = (const float*)d_in[8];
  float* out = (float*)d_out;
  (void)bk;   // bk only contributes row-constant score terms -> softmax-invariant

  const int T = 2048;
  const long long MT = 8192;                          // B*T
  const long long MM = 1048576;                       // 1024*1024

  // workspace layout (shorts); ~124 MB
  short* ws    = (short*)d_ws;
  short* ybf   = ws;                                  // 16 MB
  short* WqBf  = ybf + MT * 1024;                     // 2 MB each
  short* WkBf  = WqBf + MM;
  short* WoT   = WkBf + MM;
  short* WvBf  = WoT + MM;
  short* MTb   = WvBf + MM;                           // (Wk Wq^T) bf16
  short* WvoT  = MTb + MM;                            // ((Wv Wo)^T) bf16
  short* G     = WvoT + MM;                           // 8192x1024 bf16
  short* zT    = G + MT * 1024;                       // 1024x8192 bf16
  short* scores = zT + MT * 1024;                     // 4*T*T bf16 (32 MB)
  float* bvWo  = (float*)(scores + 4ll * T * T);      // 1024 fp32
  float* wvec  = bvWo + 1024;                         // 1024 fp32
  float* partM = wvec + 1024;                         // 4 x 1M fp32 (16 MB)
  float* partW = partM + 4ll * MM;                    // 4 x 1M fp32 (16 MB)

  // 0. zero the bias accumulator (graph-safe stream op)
  hipMemsetAsync(bvWo, 0, 1024 * sizeof(float), stream);

  // 1. ALL independent prep in one dispatch
  cvt_all<<<9280, 256, 0, stream>>>(y, Wq, Wk, Wo, Wv, bq, bv,
                                    ybf, WqBf, WkBf, WoT, WvBf, wvec, bvWo);

  // 2. both weight GEMMs (split-K x4 each) in one dispatch + one combine
  gemm_ww<<<512, 256, 0, stream>>>(WkBf, WqBf, WoT, WvBf, partM, partW);
  combine_ww<<<2048, 256, 0, stream>>>(partM, partW, MTb, WvoT);

  // 3. G = (y @ M + w)/32 : 128x64 occ-6, 1024 wgs
  gemm_g2<<<1024, 256, 0, stream>>>(ybf, MTb, G, wvec);

  // 4. merged scores (banded triangular 1088) + zT (1024): 2112 wgs, occ-6
  gemm_sz2<<<2112, 256, 0, stream>>>(G, ybf, WvoT, scores, zT);

  // 5. causal softmax in place (wlim 128-aligned for the 128-row PV tiles)
  softmax_causal_bf16_k<<<(int)MT, 256, 0, stream>>>(scores);

  // 6. out = P @ z + (bo + bv@Wo) : 128x64 occ-6, 1024 wgs
  gemm_pv<<<1024, 256, 0, stream>>>(scores, zT, out, bo, bvWo);
}

// Round 12
// 154.333 us; speedup vs baseline: 1.0390x; 1.0390x over previous
//
#include <hip/hip_runtime.h>
#include <hip/hip_bf16.h>
#include <cstdint>

#define DEVI __device__ __forceinline__

typedef __attribute__((ext_vector_type(8))) short bf16x8;
typedef __attribute__((ext_vector_type(4))) short bf16x4;
typedef __attribute__((ext_vector_type(4))) float f32x4;

DEVI short f2bf(float f) {
  unsigned u = __float_as_uint(f);
  u += 0x7fff + ((u >> 16) & 1);   // round-to-nearest-even
  return (short)(u >> 16);
}
DEVI float bf2f(short s) { return __uint_as_float(((unsigned)(unsigned short)s) << 16); }

DEVI void gl_lds16(const short* g, short* l) {
  __builtin_amdgcn_global_load_lds((const __attribute__((address_space(1))) unsigned*)g,
                                   (__attribute__((address_space(3))) unsigned*)l, 16, 0, 0);
}

// ===========================================================================
// Ladder status (R20-R27, measured), K=1024-class GEMMs:
//   occ-2 dbuf(drain0) 372-614 TF | occ-4/6 SB 662-715 TF <- structure floor
//   falsified levers on the floor: occupancy (R24), L2-band ordering (R25),
//   counted-vmcnt pipelining (R26: 54->62us regression).
// R28: non-GEMM slack attack — split-K weight path (ww + 36MB partial
// round-trip + combine dispatch) replaced by direct 64^2-tile K=1024 GEMM
// (R23-proven core), bf16 out. -1 dispatch, -36MB traffic.
// ===========================================================================

// ---------------------------------------------------------------------------
// gemm_ww64: both weight precomputes, direct (no split-K), 512 wgs.
//   job 0: MTb  = WkBf @ WqBf^T   (256 tiles of 64x64)
//   job 1: WvoT = WoT  @ WvBf^T
// 64x64 tiles, K=1024 (16 steps), occ-6.
// ---------------------------------------------------------------------------
__global__ __launch_bounds__(256, 6)
void gemm_ww64(const short* __restrict__ WkBf, const short* __restrict__ WqBf,
               const short* __restrict__ WoT, const short* __restrict__ WvBf,
               short* __restrict__ MTb, short* __restrict__ WvoT)
{
  const int orig = blockIdx.x;                 // 512 wgs
  const int xcd = orig & 7, idx8 = orig >> 3;
  const int wg = xcd * 64 + idx8;              // q8=64
  const int job = wg >> 8, rem = wg & 255;
  const int bi = rem >> 4, bj = rem & 15;

  const short* A = job ? WoT  : WkBf;
  const short* B = job ? WvBf : WqBf;
  short* C = job ? WvoT : MTb;

  __shared__ __align__(16) short lA[64 * 64];  // 8 KB
  __shared__ __align__(16) short lB[64 * 64];  // 8 KB

  const int tid = threadIdx.x, wave = tid >> 6, lane = tid & 63;
  const int wm = wave >> 1, wn = wave & 1;
  const int brow = bi * 64, bcol = bj * 64;
  const int fr = lane & 15, h = lane >> 4;

  const int ck0 = ((h ^ (fr & 7))) * 8;
  const int swc = ((tid & 7) ^ ((tid >> 3) & 7)) * 8;
  const short* pA = A + (long long)(brow + (tid >> 3)) * 1024 + swc;
  const short* pB = B + (long long)(bcol + (tid >> 3)) * 1024 + swc;

  f32x4 acc[2][2] = {};

  for (int t = 0; t < 16; ++t) {
    const long long ko = (long long)t * 64;
#pragma unroll
    for (int j = 0; j < 2; ++j)
      gl_lds16(pA + (long long)(j * 32) * 1024 + ko, &lA[j * 2048 + tid * 8]);
#pragma unroll
    for (int j = 0; j < 2; ++j)
      gl_lds16(pB + (long long)(j * 32) * 1024 + ko, &lB[j * 2048 + tid * 8]);
    __syncthreads();

    bf16x8 af[2], bg[2];
#pragma unroll
    for (int m = 0; m < 2; ++m)
      af[m] = *(const bf16x8*)&lA[(wm * 32 + m * 16 + fr) * 64 + ck0];
#pragma unroll
    for (int n = 0; n < 2; ++n)
      bg[n] = *(const bf16x8*)&lB[(wn * 32 + n * 16 + fr) * 64 + ck0];
#pragma unroll
    for (int m = 0; m < 2; ++m)
#pragma unroll
      for (int n = 0; n < 2; ++n)
        acc[m][n] = __builtin_amdgcn_mfma_f32_16x16x32_bf16(af[m], bg[n], acc[m][n], 0, 0, 0);
#pragma unroll
    for (int m = 0; m < 2; ++m)
      af[m] = *(const bf16x8*)&lA[((wm * 32 + m * 16 + fr) * 64 + ck0) ^ 32];
#pragma unroll
    for (int n = 0; n < 2; ++n)
      bg[n] = *(const bf16x8*)&lB[((wn * 32 + n * 16 + fr) * 64 + ck0) ^ 32];
#pragma unroll
    for (int m = 0; m < 2; ++m)
#pragma unroll
      for (int n = 0; n < 2; ++n)
        acc[m][n] = __builtin_amdgcn_mfma_f32_16x16x32_bf16(af[m], bg[n], acc[m][n], 0, 0, 0);
    __syncthreads();
  }

  const int lrow = h * 4;
#pragma unroll
  for (int m = 0; m < 2; ++m) {
    const int row = brow + wm * 32 + m * 16 + lrow;
#pragma unroll
    for (int j = 0; j < 4; ++j)
#pragma unroll
      for (int n = 0; n < 2; ++n)
        C[(long long)(row + j) * 1024 + bcol + wn * 32 + n * 16 + fr] = f2bf(acc[m][n][j]);
  }
}

// ---------------------------------------------------------------------------
// gemm_g2: G = (ybf @ MTb^T + wvec)/32. 128x64 tiles, occ-6, 1024 wgs.
// ---------------------------------------------------------------------------
__global__ __launch_bounds__(256, 6)
void gemm_g2(const short* __restrict__ ybf, const short* __restrict__ MTb,
             short* __restrict__ G, const float* __restrict__ wvec)
{
  const int orig = blockIdx.x;                  // 1024 wgs
  const int xcd = orig & 7, idx8 = orig >> 3;
  const int wg = xcd * 128 + idx8;              // q8=128
  const int bi = wg >> 4, bj = wg & 15;         // 64 row-tiles x 16 col-tiles

  __shared__ __align__(16) short lA[128 * 64];  // 16 KB
  __shared__ __align__(16) short lB[64 * 64];   // 8 KB

  const int tid = threadIdx.x, wave = tid >> 6, lane = tid & 63;
  const int wr = wave >> 1, wc = wave & 1;
  const int brow = bi * 128, bcol = bj * 64;
  const int fr = lane & 15, h = lane >> 4;

  const int ck0 = ((h ^ (fr & 7))) * 8;
  const int swc = ((tid & 7) ^ ((tid >> 3) & 7)) * 8;
  const short* pA = ybf + (long long)(brow + (tid >> 3)) * 1024 + swc;
  const short* pB = MTb + (long long)(bcol + (tid >> 3)) * 1024 + swc;

  f32x4 acc[4][2] = {};

  for (int t = 0; t < 16; ++t) {
    const long long ko = (long long)t * 64;
#pragma unroll
    for (int j = 0; j < 4; ++j)
      gl_lds16(pA + (long long)(j * 32) * 1024 + ko, &lA[j * 2048 + tid * 8]);
#pragma unroll
    for (int j = 0; j < 2; ++j)
      gl_lds16(pB + (long long)(j * 32) * 1024 + ko, &lB[j * 2048 + tid * 8]);
    __syncthreads();

    bf16x8 af[4], bg[2];
#pragma unroll
    for (int m = 0; m < 4; ++m)
      af[m] = *(const bf16x8*)&lA[(wr * 64 + m * 16 + fr) * 64 + ck0];
#pragma unroll
    for (int n = 0; n < 2; ++n)
      bg[n] = *(const bf16x8*)&lB[(wc * 32 + n * 16 + fr) * 64 + ck0];
#pragma unroll
    for (int m = 0; m < 4; ++m)
#pragma unroll
      for (int n = 0; n < 2; ++n)
        acc[m][n] = __builtin_amdgcn_mfma_f32_16x16x32_bf16(af[m], bg[n], acc[m][n], 0, 0, 0);
#pragma unroll
    for (int m = 0; m < 4; ++m)
      af[m] = *(const bf16x8*)&lA[((wr * 64 + m * 16 + fr) * 64 + ck0) ^ 32];
#pragma unroll
    for (int n = 0; n < 2; ++n)
      bg[n] = *(const bf16x8*)&lB[((wc * 32 + n * 16 + fr) * 64 + ck0) ^ 32];
#pragma unroll
    for (int m = 0; m < 4; ++m)
#pragma unroll
      for (int n = 0; n < 2; ++n)
        acc[m][n] = __builtin_amdgcn_mfma_f32_16x16x32_bf16(af[m], bg[n], acc[m][n], 0, 0, 0);
    __syncthreads();
  }

  const int lrow = h * 4;
  int colg[2]; float bvv[2];
#pragma unroll
  for (int n = 0; n < 2; ++n) {
    colg[n] = bcol + wc * 32 + n * 16 + fr;
    bvv[n] = wvec[colg[n]];
  }
#pragma unroll
  for (int m = 0; m < 4; ++m) {
    const int row = brow + wr * 64 + m * 16 + lrow;
#pragma unroll
    for (int j = 0; j < 4; ++j)
#pragma unroll
      for (int n = 0; n < 2; ++n)
        G[(long long)(row + j) * 1024 + colg[n]] =
            f2bf((acc[m][n][j] + bvv[n]) * (1.f / 32.f));
  }
}

// ---------------------------------------------------------------------------
// gemm_sz2: merged scores+zT, 128x64 tiles, occ-6, 2112 wgs (R25 version —
// proven 54.2us dispatch; all three further levers falsified).
// ---------------------------------------------------------------------------
__global__ __launch_bounds__(256, 6)
void gemm_sz2(const short* __restrict__ G, const short* __restrict__ ybf,
              const short* __restrict__ WvoT, short* __restrict__ scores,
              short* __restrict__ zT)
{
  const int orig = blockIdx.x;                  // 2112 wgs
  const int xcd = orig & 7, idx8 = orig >> 3;
  const int wg = xcd * 264 + idx8;              // q8=264

  const short *A, *B; short* C; int ldc, bi, bj;
  if (wg < 1088) {
    const int z = wg / 272, t = wg - z * 272;
    // banded decode: k = band (4 bi-rows), u = index within band
    const int k = (t >= 20) + (t >= 72) + (t >= 156);
    const int u = t - (16 * k * k + 4 * k);
    int r, col;
    if (u < 32 * k) {                 // full 8-col blocks
      const int cb = u >> 5, w = u & 31;
      r = w >> 3; col = cb * 8 + (w & 7);
    } else {                          // ragged diagonal block (2/4/6/8 cols)
      const int u2 = u - 32 * k;
      r = (u2 >= 2) + (u2 >= 6) + (u2 >= 12);
      const int cum = (r == 0) ? 0 : (r == 1) ? 2 : (r == 2) ? 6 : 12;
      col = 8 * k + (u2 - cum);
    }
    bi = 4 * k + r; bj = col;
    A = G + (long long)z * 2048 * 1024;
    B = ybf + (long long)z * 2048 * 1024;
    C = scores + (long long)z * 2048 * 2048;
    ldc = 2048;
  } else {
    const int lwg = wg - 1088;
    bi = lwg >> 7; bj = lwg & 127;
    A = WvoT; B = ybf; C = zT; ldc = 8192;
  }

  __shared__ __align__(16) short lA[128 * 64];  // 16 KB
  __shared__ __align__(16) short lB[64 * 64];   // 8 KB

  const int tid = threadIdx.x, wave = tid >> 6, lane = tid & 63;
  const int wr = wave >> 1, wc = wave & 1;
  const int brow = bi * 128, bcol = bj * 64;
  const int fr = lane & 15, h = lane >> 4;

  const int ck0 = ((h ^ (fr & 7))) * 8;
  const int swc = ((tid & 7) ^ ((tid >> 3) & 7)) * 8;
  const short* pA = A + (long long)(brow + (tid >> 3)) * 1024 + swc;
  const short* pB = B + (long long)(bcol + (tid >> 3)) * 1024 + swc;

  f32x4 acc[4][2] = {};

  for (int t = 0; t < 16; ++t) {
    const long long ko = (long long)t * 64;
#pragma unroll
    for (int j = 0; j < 4; ++j)
      gl_lds16(pA + (long long)(j * 32) * 1024 + ko, &lA[j * 2048 + tid * 8]);
#pragma unroll
    for (int j = 0; j < 2; ++j)
      gl_lds16(pB + (long long)(j * 32) * 1024 + ko, &lB[j * 2048 + tid * 8]);
    __syncthreads();

    bf16x8 af[4], bg[2];
#pragma unroll
    for (int m = 0; m < 4; ++m)
      af[m] = *(const bf16x8*)&lA[(wr * 64 + m * 16 + fr) * 64 + ck0];
#pragma unroll
    for (int n = 0; n < 2; ++n)
      bg[n] = *(const bf16x8*)&lB[(wc * 32 + n * 16 + fr) * 64 + ck0];
#pragma unroll
    for (int m = 0; m < 4; ++m)
#pragma unroll
      for (int n = 0; n < 2; ++n)
        acc[m][n] = __builtin_amdgcn_mfma_f32_16x16x32_bf16(af[m], bg[n], acc[m][n], 0, 0, 0);
#pragma unroll
    for (int m = 0; m < 4; ++m)
      af[m] = *(const bf16x8*)&lA[((wr * 64 + m * 16 + fr) * 64 + ck0) ^ 32];
#pragma unroll
    for (int n = 0; n < 2; ++n)
      bg[n] = *(const bf16x8*)&lB[((wc * 32 + n * 16 + fr) * 64 + ck0) ^ 32];
#pragma unroll
    for (int m = 0; m < 4; ++m)
#pragma unroll
      for (int n = 0; n < 2; ++n)
        acc[m][n] = __builtin_amdgcn_mfma_f32_16x16x32_bf16(af[m], bg[n], acc[m][n], 0, 0, 0);
    __syncthreads();
  }

  const int lrow = h * 4;
  int colg[2];
#pragma unroll
  for (int n = 0; n < 2; ++n) colg[n] = bcol + wc * 32 + n * 16 + fr;
#pragma unroll
  for (int m = 0; m < 4; ++m) {
    const int row = brow + wr * 64 + m * 16 + lrow;
#pragma unroll
    for (int j = 0; j < 4; ++j)
#pragma unroll
      for (int n = 0; n < 2; ++n)
        C[(long long)(row + j) * ldc + colg[n]] = f2bf(acc[m][n][j]);
  }
}

// ===========================================================================
// PV: 128x64 tiles (proven core), 1024 wgs, parity-mixed balanced decode.
// Causal kend=(bi+1)*128. out = P @ z + (bo + bvWo), final fp32.
// ===========================================================================
__global__ __launch_bounds__(256, 6)
void gemm_pv(const short* __restrict__ scores, const short* __restrict__ zT,
             float* __restrict__ out, const float* __restrict__ bo,
             const float* __restrict__ bvWo)
{
  const int orig = blockIdx.x;                 // 1024 wgs
  const int xcd = orig & 7, idx8 = orig >> 3;  // idx8 in [0,128)
  const int z = xcd >> 1;                      // batch 0..3
  const int bi = ((idx8 >> 4) << 1) | ((xcd & 1) ^ (idx8 & 1));  // 0..15
  const int bj = idx8 & 15;                    // 0..15

  const short* A = scores + (long long)z * 2048 * 2048;
  const int nt = 2 * (bi + 1);                 // kend = (bi+1)*128, causal

  __shared__ __align__(16) short lA[128 * 64]; // 16 KB
  __shared__ __align__(16) short lB[64 * 64];  // 8 KB

  const int tid = threadIdx.x, wave = tid >> 6, lane = tid & 63;
  const int wr = wave >> 1, wc = wave & 1;
  const int brow = bi * 128, bcol = bj * 64;
  const int fr = lane & 15, h = lane >> 4;

  const int ck0 = ((h ^ (fr & 7))) * 8;
  const int swc = ((tid & 7) ^ ((tid >> 3) & 7)) * 8;
  const short* pA = A + (long long)(brow + (tid >> 3)) * 2048 + swc;
  const short* pB = zT + (long long)(bcol + (tid >> 3)) * 8192 + z * 2048 + swc;

  f32x4 acc[4][2] = {};

  for (int t = 0; t < nt; ++t) {
    const long long ko = (long long)t * 64;
#pragma unroll
    for (int j = 0; j < 4; ++j)
      gl_lds16(pA + (long long)(j * 32) * 2048 + ko, &lA[j * 2048 + tid * 8]);
#pragma unroll
    for (int j = 0; j < 2; ++j)
      gl_lds16(pB + (long long)(j * 32) * 8192 + ko, &lB[j * 2048 + tid * 8]);
    __syncthreads();

    bf16x8 af[4], bg[2];
#pragma unroll
    for (int m = 0; m < 4; ++m)
      af[m] = *(const bf16x8*)&lA[(wr * 64 + m * 16 + fr) * 64 + ck0];
#pragma unroll
    for (int n = 0; n < 2; ++n)
      bg[n] = *(const bf16x8*)&lB[(wc * 32 + n * 16 + fr) * 64 + ck0];
#pragma unroll
    for (int m = 0; m < 4; ++m)
#pragma unroll
      for (int n = 0; n < 2; ++n)
        acc[m][n] = __builtin_amdgcn_mfma_f32_16x16x32_bf16(af[m], bg[n], acc[m][n], 0, 0, 0);
#pragma unroll
    for (int m = 0; m < 4; ++m)
      af[m] = *(const bf16x8*)&lA[((wr * 64 + m * 16 + fr) * 64 + ck0) ^ 32];
#pragma unroll
    for (int n = 0; n < 2; ++n)
      bg[n] = *(const bf16x8*)&lB[((wc * 32 + n * 16 + fr) * 64 + ck0) ^ 32];
#pragma unroll
    for (int m = 0; m < 4; ++m)
#pragma unroll
      for (int n = 0; n < 2; ++n)
        acc[m][n] = __builtin_amdgcn_mfma_f32_16x16x32_bf16(af[m], bg[n], acc[m][n], 0, 0, 0);
    __syncthreads();
  }

  const int lrow = h * 4;
  int colg[2]; float bvv[2];
#pragma unroll
  for (int n = 0; n < 2; ++n) {
    colg[n] = bcol + wc * 32 + n * 16 + fr;
    bvv[n] = bo[colg[n]] + bvWo[colg[n]];
  }
#pragma unroll
  for (int m = 0; m < 4; ++m) {
    const int row = brow + wr * 64 + m * 16 + lrow;
#pragma unroll
    for (int j = 0; j < 4; ++j)
#pragma unroll
      for (int n = 0; n < 2; ++n)
        out[(long long)(z * 2048 + row + j) * 1024 + colg[n]] = acc[m][n][j] + bvv[n];
  }
}

// ---------------------------------------------------------------------------
// Causal-trimmed softmax. wlim 128-aligned: PV's 128-row tiles read cols
// < (bi+1)*128, so the masked band up to the 128 boundary must hold zeros.
__global__ __launch_bounds__(256)
void softmax_causal_bf16_k(short* __restrict__ sc)
{
  const int T = 2048;
  const long long row = blockIdx.x;
  const int t = (int)(row & (T - 1));
  short* ps = sc + row * (long long)T;
  const int tid = threadIdx.x, wave = tid >> 6, lane = tid & 63;
  const int c0 = tid * 8;
  const int wlim = ((t >> 7) + 1) << 7;   // exclusive write limit, 128-aligned

  bf16x8 v = {};
  if (c0 <= t) v = *(const bf16x8*)&ps[c0];
  float x[8];
#pragma unroll
  for (int j = 0; j < 8; ++j) x[j] = bf2f(v[j]);

  float mx = -3.0e38f;
#pragma unroll
  for (int j = 0; j < 8; ++j) if (c0 + j <= t) mx = fmaxf(mx, x[j]);
#pragma unroll
  for (int o = 32; o; o >>= 1) mx = fmaxf(mx, __shfl_xor(mx, o, 64));
  __shared__ float red[8];
  if (lane == 0) red[wave] = mx;
  __syncthreads();
  const float M = fmaxf(fmaxf(red[0], red[1]), fmaxf(red[2], red[3]));

  float e[8], s = 0.f;
#pragma unroll
  for (int j = 0; j < 8; ++j) { e[j] = (c0 + j <= t) ? __expf(x[j] - M) : 0.f; s += e[j]; }
#pragma unroll
  for (int o = 32; o; o >>= 1) s += __shfl_xor(s, o, 64);
  if (lane == 0) red[4 + wave] = s;
  __syncthreads();
  const float inv = 1.f / (red[4] + red[5] + red[6] + red[7]);

  if (c0 < wlim) {
    bf16x8 ov;
#pragma unroll
    for (int j = 0; j < 8; ++j) ov[j] = f2bf(e[j] * inv);
    *(bf16x8*)&ps[c0] = ov;
  }
}

// ---------------------------------------------------------------------------
// cvt_all: ALL independent prep work in one dispatch (9280 wgs):
//   wg <  4096: y fp32 -> ybf
//   wg <  8192: weight converts (Wq/Wk/Wv plain, Wo transpose)
//   wg <  9216: wkbq GEMV row (wvec = Wk @ bq)
//   wg <  9280: bias_fold (bvWo += bv block @ Wo, atomics; pre-zeroed)
// ---------------------------------------------------------------------------
__global__ __launch_bounds__(256)
void cvt_all(const float* __restrict__ y, const float* __restrict__ Wq,
             const float* __restrict__ Wk, const float* __restrict__ Wo,
             const float* __restrict__ Wv, const float* __restrict__ bq,
             const float* __restrict__ bv,
             short* __restrict__ ybf, short* __restrict__ WqBf,
             short* __restrict__ WkBf, short* __restrict__ WoT,
             short* __restrict__ WvBf, float* __restrict__ wvec,
             float* __restrict__ bvWo)
{
  const int wg = blockIdx.x, tid = threadIdx.x;
  __shared__ float tile[32][33];
  __shared__ float red[4];

  if (wg < 4096) {                    // ---- y convert
    const long long i = (long long)wg * 256 + tid;
    const float4 v0 = ((const float4*)y)[i * 2];
    const float4 v1 = ((const float4*)y)[i * 2 + 1];
    bf16x8 o;
    o[0] = f2bf(v0.x); o[1] = f2bf(v0.y); o[2] = f2bf(v0.z); o[3] = f2bf(v0.w);
    o[4] = f2bf(v1.x); o[5] = f2bf(v1.y); o[6] = f2bf(v1.z); o[7] = f2bf(v1.w);
    ((bf16x8*)ybf)[i] = o;
  } else if (wg < 8192) {             // ---- weight converts
    const int lwg = wg - 4096;
    const int bx = lwg & 31, by = (lwg >> 5) & 31, bz = lwg >> 10;
    const int tx = tid & 31, ty = tid >> 5;
    const int r0 = by * 32, c0 = bx * 32;
    if (bz != 2) {
      const float* in = (bz == 0) ? Wq : (bz == 1 ? Wk : Wv);
      short* out      = (bz == 0) ? WqBf : (bz == 1 ? WkBf : WvBf);
#pragma unroll
      for (int i = 0; i < 4; ++i)
        out[(long long)(r0 + ty + 8 * i) * 1024 + c0 + tx] =
            f2bf(in[(long long)(r0 + ty + 8 * i) * 1024 + c0 + tx]);
    } else {
#pragma unroll
      for (int i = 0; i < 4; ++i)
        tile[ty + 8 * i][tx] = Wo[(long long)(r0 + ty + 8 * i) * 1024 + c0 + tx];
      __syncthreads();
#pragma unroll
      for (int i = 0; i < 4; ++i)
        WoT[(long long)(c0 + ty + 8 * i) * 1024 + r0 + tx] = f2bf(tile[tx][ty + 8 * i]);
    }
  } else if (wg < 9216) {             // ---- wkbq GEMV
    const int row = wg - 8192;
    const float4 a = ((const float4*)(Wk + (long long)row * 1024))[tid];
    const float4 b = ((const float4*)bq)[tid];
    float s = a.x * b.x + a.y * b.y + a.z * b.z + a.w * b.w;
#pragma unroll
    for (int o = 32; o; o >>= 1) s += __shfl_xor(s, o, 64);
    if ((tid & 63) == 0) red[tid >> 6] = s;
    __syncthreads();
    if (tid == 0) wvec[row] = red[0] + red[1] + red[2] + red[3];
  } else {                            // ---- bias fold (bvWo pre-zeroed)
    const int r0 = (wg - 9216) * 16;
    const int c4 = tid;
    float4 acc = make_float4(0.f, 0.f, 0.f, 0.f);
    for (int r = 0; r < 16; ++r) {
      const float s = bv[r0 + r];
      const float4 w = ((const float4*)(Wo + (long long)(r0 + r) * 1024))[c4];
      acc.x += s * w.x; acc.y += s * w.y; acc.z += s * w.z; acc.w += s * w.w;
    }
    atomicAdd(&bvWo[c4 * 4 + 0], acc.x);
    atomicAdd(&bvWo[c4 * 4 + 1], acc.y);
    atomicAdd(&bvWo[c4 * 4 + 2], acc.z);
    atomicAdd(&bvWo[c4 * 4 + 3], acc.w);
  }
}

// ---------------------------------------------------------------------------
extern "C" void kernel_launch(void* const* d_in, const int* in_sizes, int n_in,
                              void* d_out, int out_size, void* d_ws, size_t ws_size,
                              hipStream_t stream)
{
  (void)in_sizes; (void)n_in; (void)out_size; (void)ws_size;
  const float* y  = (const float*)d_in[0];
  const float* Wq = (const float*)d_in[1];
  const float* bq = (const float*)d_in[2];
  const float* Wk = (const float*)d_in[3];
  const float* bk = (const float*)d_in[4];
  const float* Wv = (const float*)d_in[5];
  const float* bv = (const float*)d_in[6];
  const float* Wo = (const float*)d_in[7];
  const float* bo = (const float*)d_in[8];
  float* out = (float*)d_out;
  (void)bk;   // bk only contributes row-constant score terms -> softmax-invariant

  const int T = 2048;
  const long long MT = 8192;                          // B*T
  const long long MM = 1048576;                       // 1024*1024

  // workspace layout (shorts); ~92 MB
  short* ws    = (short*)d_ws;
  short* ybf   = ws;                                  // 16 MB
  short* WqBf  = ybf + MT * 1024;                     // 2 MB each
  short* WkBf  = WqBf + MM;
  short* WoT   = WkBf + MM;
  short* WvBf  = WoT + MM;
  short* MTb   = WvBf + MM;                           // (Wk Wq^T) bf16
  short* WvoT  = MTb + MM;                            // ((Wv Wo)^T) bf16
  short* G     = WvoT + MM;                           // 8192x1024 bf16
  short* zT    = G + MT * 1024;                       // 1024x8192 bf16
  short* scores = zT + MT * 1024;                     // 4*T*T bf16 (32 MB)
  float* bvWo  = (float*)(scores + 4ll * T * T);      // 1024 fp32
  float* wvec  = bvWo + 1024;                         // 1024 fp32

  // 0. zero the bias accumulator (graph-safe stream op)
  hipMemsetAsync(bvWo, 0, 1024 * sizeof(float), stream);

  // 1. ALL independent prep in one dispatch
  cvt_all<<<9280, 256, 0, stream>>>(y, Wq, Wk, Wo, Wv, bq, bv,
                                    ybf, WqBf, WkBf, WoT, WvBf, wvec, bvWo);

  // 2. both weight GEMMs direct (no split-K, no combine): 512 wgs
  gemm_ww64<<<512, 256, 0, stream>>>(WkBf, WqBf, WoT, WvBf, MTb, WvoT);

  // 3. G = (y @ M + w)/32 : 128x64 occ-6, 1024 wgs
  gemm_g2<<<1024, 256, 0, stream>>>(ybf, MTb, G, wvec);

  // 4. merged scores (banded triangular 1088) + zT (1024): 2112 wgs, occ-6
  gemm_sz2<<<2112, 256, 0, stream>>>(G, ybf, WvoT, scores, zT);

  // 5. causal softmax in place (wlim 128-aligned for the 128-row PV tiles)
  softmax_causal_bf16_k<<<(int)MT, 256, 0, stream>>>(scores);

  // 6. out = P @ z + (bo + bv@Wo) : 128x64 occ-6, 1024 wgs
  gemm_pv<<<1024, 256, 0, stream>>>(scores, zT, out, bo, bvWo);
}